// Round 10
// baseline (149.565 us; speedup 1.0000x reference)
//
#include <hip/hip_runtime.h>
#include <hip/hip_bf16.h>

#define D_FEAT 64
#define NPB 128              // nodes per bucket (dst >> 7)
#define NPB_SHIFT 7
#define NL1 256              // level-1 blocks
#define MAX_NB 1024          // max buckets supported by LDS arrays
#define SCAN_T 256
#define SCAN_PER_T 8
#define SCAN_CHUNK (SCAN_T * SCAN_PER_T)   // 2048
#define SRC_BITS 17
#define SRC_MASK 0x1FFFF
#define CVT_BLOCKS 2048
#define W_SCALE 32768.0f
#define W_INV (1.0f / 32768.0f)

typedef unsigned int uint_t;

__device__ inline unsigned short f32_to_bf16_rn(float f) {
    uint_t x = __float_as_uint(f);
    uint_t r = (x + 0x7fffu + ((x >> 16) & 1u)) >> 16;   // round-to-nearest-even
    return (unsigned short)r;
}

// ---------- PRE: fused dst-bucket histogram + (optional) bf16 convert ----------
// blocks [0, NL1): histogram of dst buckets into counts_T (transposed, +1 shift)
// blocks [NL1, NL1+CVT_BLOCKS): grid-stride convert input rows -> packed bf16x2
// block 0 additionally zeros pub[256]+ticket[1] for the lookback scan.
__global__ void mp_pre_kernel(const int* __restrict__ edst,
                              int* __restrict__ counts_T,
                              int n_edges, int nb_buckets,
                              int* __restrict__ pubtick,          // 257 ints
                              const float2* __restrict__ in2,
                              uint_t* __restrict__ bfrow, int ncvt) {
    __shared__ int hist[MAX_NB];
    int t = threadIdx.x;
    if (blockIdx.x < NL1) {
        if (blockIdx.x == 0)
            for (int i = t; i < 257; i += blockDim.x) pubtick[i] = 0;
        for (int k = t; k < nb_buckets; k += blockDim.x) hist[k] = 0;
        __syncthreads();
        int epb = (n_edges + NL1 - 1) / NL1;
        int lo = blockIdx.x * epb;
        int hi = min(n_edges, lo + epb);
        for (int i = lo + t; i < hi; i += blockDim.x)
            atomicAdd(&hist[edst[i] >> NPB_SHIFT], 1);
        __syncthreads();
        for (int k = t; k < nb_buckets; k += blockDim.x)
            counts_T[k * NL1 + blockIdx.x + 1] = hist[k];
        if (blockIdx.x == 0 && t == 0) counts_T[0] = 0;
    } else {
        int g0 = (blockIdx.x - NL1) * blockDim.x + t;
        int stride = CVT_BLOCKS * blockDim.x;
        for (int g = g0; g < ncvt; g += stride) {
            float2 v = in2[g];
            bfrow[g] = (uint_t)f32_to_bf16_rn(v.x) |
                       ((uint_t)f32_to_bf16_rn(v.y) << 16);
        }
    }
}

// ---------- single-pass decoupled-lookback inclusive scan ----------
// pub[b] = (inclusive prefix through chunk b) + 1  (0 = not ready).
// Ticketing makes chunk order independent of HW dispatch order.
__global__ void mp_scanlb_kernel(int* __restrict__ a, int n,
                                 int* __restrict__ pub, int* __restrict__ ticket) {
    __shared__ int tsum[SCAN_T];
    __shared__ int bid_s, prev_s;
    int t = threadIdx.x;
    if (t == 0) bid_s = atomicAdd(ticket, 1);
    __syncthreads();
    int bid = bid_s;
    int base = bid * SCAN_CHUNK + t * SCAN_PER_T;
    int v[SCAN_PER_T];
    int s = 0;
    #pragma unroll
    for (int j = 0; j < SCAN_PER_T; ++j) {
        int idx = base + j;
        v[j] = (idx < n) ? a[idx] : 0;
        s += v[j];
    }
    tsum[t] = s;
    __syncthreads();
    #pragma unroll
    for (int off = 1; off < SCAN_T; off <<= 1) {
        int u = (t >= off) ? tsum[t - off] : 0;
        __syncthreads();
        tsum[t] += u;
        __syncthreads();
    }
    if (t == SCAN_T - 1) {
        int total = tsum[t];
        int prev = 0;
        if (bid > 0) {
            int p;
            while ((p = atomicAdd(&pub[bid - 1], 0)) == 0) ;
            prev = p - 1;
        }
        atomicExch(&pub[bid], prev + total + 1);
        prev_s = prev;
    }
    __syncthreads();
    int run = prev_s + ((t == 0) ? 0 : tsum[t - 1]);
    #pragma unroll
    for (int j = 0; j < SCAN_PER_T; ++j) {
        int idx = base + j;
        run += v[j];
        if (idx < n) a[idx] = run;
    }
}

// ---------- Level 1b: scatter edges into bucket order via LDS cursors ----------
__global__ void mp_l1scatter_kernel(const int* __restrict__ esrc,
                                    const int* __restrict__ edst,
                                    const float* __restrict__ ew,
                                    const int* __restrict__ counts_T,
                                    int2* __restrict__ elistA,
                                    int n_edges, int nb_buckets) {
    __shared__ int cur[MAX_NB];
    int t = threadIdx.x;
    for (int k = t; k < nb_buckets; k += blockDim.x)
        cur[k] = counts_T[k * NL1 + blockIdx.x];
    __syncthreads();
    int epb = (n_edges + NL1 - 1) / NL1;
    int lo = blockIdx.x * epb;
    int hi = min(n_edges, lo + epb);
    for (int i = lo + t; i < hi; i += blockDim.x) {
        int d = edst[i];
        int pos = atomicAdd(&cur[d >> NPB_SHIFT], 1);
        elistA[pos] = make_int2(esrc[i] | ((d & (NPB - 1)) << SRC_BITS),
                                __float_as_int(ew[i]));
    }
}

// ---------- Level 2: per-bucket counting sort -> per-node CSR, 4B records ----------
// elistB4[pos] = src(17b) | w_fixed15 << 17
__global__ void mp_l2sort_kernel(const int2* __restrict__ elistA,
                                 const int* __restrict__ counts_T,
                                 uint_t* __restrict__ elistB4,
                                 int* __restrict__ node_start,
                                 int n_nodes, int n_edges, int nb_buckets) {
    __shared__ int nh[NPB];
    __shared__ int cur[NPB];
    int k = blockIdx.x;
    int t = threadIdx.x;
    if (t < NPB) nh[t] = 0;
    __syncthreads();

    int base = counts_T[k * NL1];
    int end  = (k + 1 < nb_buckets) ? counts_T[(k + 1) * NL1] : n_edges;
    int cnt  = end - base;

    for (int i = t; i < cnt; i += 256)
        atomicAdd(&nh[elistA[base + i].x >> SRC_BITS], 1);
    __syncthreads();

    #pragma unroll
    for (int off = 1; off < NPB; off <<= 1) {
        int v = (t < NPB && t >= off) ? nh[t - off] : 0;
        __syncthreads();
        if (t < NPB) nh[t] += v;
        __syncthreads();
    }

    if (t < NPB) {
        int excl = base + ((t == 0) ? 0 : nh[t - 1]);
        cur[t] = excl;
        int g = k * NPB + t;
        if (g < n_nodes) node_start[g] = excl;
    }
    if (k == nb_buckets - 1 && t == 0) node_start[n_nodes] = n_edges;
    __syncthreads();

    for (int i = t; i < cnt; i += 256) {
        int2 r = elistA[base + i];
        int pos = atomicAdd(&cur[r.x >> SRC_BITS], 1);
        int w15 = (int)(__int_as_float(r.y) * W_SCALE + 0.5f);
        w15 = min(32767, max(0, w15));
        elistB4[pos] = (uint_t)(r.x & SRC_MASK) | ((uint_t)w15 << 17);
    }
}

// ---------- standalone cvt (used only when bfrow overlays elistA) ----------
__global__ void mp_cvt_kernel(const float2* __restrict__ in2,
                              uint_t* __restrict__ bfrow, int n) {
    int g = blockIdx.x * blockDim.x + threadIdx.x;
    if (g >= n) return;
    float2 v = in2[g];
    bfrow[g] = (uint_t)f32_to_bf16_rn(v.x) | ((uint_t)f32_to_bf16_rn(v.y) << 16);
}

// ---------- Gather (bf16 rows), 4B records, uniform shfl ----------
__global__ void mp_gather3_kernel(const float* __restrict__ input,
                                  const uint_t* __restrict__ bfrow,
                                  const int* __restrict__ node_start,
                                  const uint_t* __restrict__ elist4,
                                  float* __restrict__ out, int n_nodes) {
    int wid = (blockIdx.x * blockDim.x + threadIdx.x) >> 6;
    if (wid >= n_nodes) return;
    int lane = threadIdx.x & 63;
    int h = lane >> 5;
    int l5 = lane & 31;
    int b = node_start[wid];
    int cnt = node_start[wid + 1] - b;

    float ax = 0.0f, ay = 0.0f;
    for (int cbase = 0; cbase < cnt; cbase += 64) {
        int m = min(64, cnt - cbase);                  // >= 1, wave-uniform
        int rv = (int)elist4[b + cbase + min(lane, m - 1)];   // all lanes active
        int jp = 0;
        for (; jp + 16 <= m; jp += 16) {               // full 16-edge groups
            int   s[8];
            float w[8];
            uint_t u[8];
            #pragma unroll
            for (int q = 0; q < 8; ++q) {
                uint_t vq = (uint_t)__shfl(rv, jp + 2 * q + h, 64);
                s[q] = (int)(vq & SRC_MASK);
                w[q] = (float)(vq >> 17) * W_INV;
            }
            #pragma unroll
            for (int q = 0; q < 8; ++q)
                u[q] = bfrow[((uint_t)s[q] << 5) + l5];
            #pragma unroll
            for (int q = 0; q < 8; ++q) {
                ax = fmaf(__uint_as_float(u[q] << 16), w[q], ax);
                ay = fmaf(__uint_as_float(u[q] & 0xffff0000u), w[q], ay);
            }
        }
        // uniform tail: identical trip count in both halves; clamp shfl lane,
        // zero phantom weight.
        for (int j = jp; j < m; j += 2) {
            int jj = j + h;
            int jc = (jj < m) ? jj : (m - 1);
            uint_t vq = (uint_t)__shfl(rv, jc, 64);
            int sj = (int)(vq & SRC_MASK);
            float wj = (float)(vq >> 17) * W_INV;
            if (jj >= m) wj = 0.0f;
            uint_t uj = bfrow[((uint_t)sj << 5) + l5];
            ax = fmaf(__uint_as_float(uj << 16), wj, ax);
            ay = fmaf(__uint_as_float(uj & 0xffff0000u), wj, ay);
        }
    }
    ax += __shfl_xor(ax, 32, 64);
    ay += __shfl_xor(ay, 32, 64);
    if (h == 0) {
        float2 inp = ((const float2*)input)[((long long)wid << 5) + l5];
        float2 o;
        o.x = inp.x + ax;
        o.y = inp.y + ay;
        ((float2*)out)[((long long)wid << 5) + l5] = o;
    }
}

// ---------- Gather (f32 rows) fallback tier, 4B records ----------
__global__ void mp_gather2_kernel(const float* __restrict__ input,
                                  const int* __restrict__ node_start,
                                  const uint_t* __restrict__ elist4,
                                  float* __restrict__ out, int n_nodes) {
    int wid = (blockIdx.x * blockDim.x + threadIdx.x) >> 6;
    if (wid >= n_nodes) return;
    int lane = threadIdx.x & 63;
    int b = node_start[wid], e_end = node_start[wid + 1];
    float acc = input[(long long)wid * D_FEAT + lane];
    for (int i = b; i < e_end; ++i) {
        uint_t r = elist4[i];
        float w = (float)(r >> 17) * W_INV;
        acc += input[(long long)(r & SRC_MASK) * D_FEAT + lane] * w;
    }
    out[(long long)wid * D_FEAT + lane] = acc;
}

// ---------- last-resort fallback (atomic scatter) ----------
__global__ void mp_copy_kernel(const float4* __restrict__ in,
                               float4* __restrict__ out, int n4) {
    int i = blockIdx.x * blockDim.x + threadIdx.x;
    if (i < n4) out[i] = in[i];
}

__global__ void mp_scatter_kernel(const float* __restrict__ input,
                                  const float* __restrict__ ew,
                                  const int* __restrict__ esrc,
                                  const int* __restrict__ edst,
                                  float* __restrict__ out, int n_edges) {
    int tid = blockIdx.x * blockDim.x + threadIdx.x;
    int e = tid >> 6;
    if (e >= n_edges) return;
    int lane = tid & 63;
    float v = input[(long long)esrc[e] * D_FEAT + lane] * ew[e];
    atomicAdd(&out[(long long)edst[e] * D_FEAT + lane], v);
}

extern "C" void kernel_launch(void* const* d_in, const int* in_sizes, int n_in,
                              void* d_out, int out_size, void* d_ws, size_t ws_size,
                              hipStream_t stream) {
    const float* input = (const float*)d_in[0];
    const float* ew    = (const float*)d_in[1];
    const int* esrc    = (const int*)d_in[2];
    const int* edst    = (const int*)d_in[3];
    float* out = (float*)d_out;

    int n_nodes = in_sizes[0] / D_FEAT;   // 100000
    int n_edges = in_sizes[1];            // 1600000

    int nb_buckets = (n_nodes + NPB - 1) / NPB;          // 782
    int n_scan = nb_buckets * NL1 + 1;                   // 200193
    int nbs = (n_scan + SCAN_CHUNK - 1) / SCAN_CHUNK;    // 98

    // ws: counts_T[n_scan] | pub[256] | ticket[1] | node_start[n+1] | pad
    //     | elistA (8B*E) | elistB4 (4B*E) | bfrow (12.8MB, dedicated or overlay A)
    size_t head_ints = (size_t)n_scan + 257 + (size_t)n_nodes + 1;
    size_t elist_off = (head_ints * 4 + 255) & ~(size_t)255;
    size_t elistA_bytes = (size_t)n_edges * 8;
    size_t elistB_bytes = (size_t)n_edges * 4;
    size_t needed_base = elist_off + elistA_bytes + elistB_bytes;
    size_t bf_bytes = (size_t)n_nodes * (D_FEAT * 2);    // 128B per row
    size_t needed_ded = needed_base + bf_bytes;

    bool sort_ok = (ws_size >= needed_base) && (nb_buckets <= MAX_NB) &&
                   (n_nodes <= (1 << SRC_BITS)) && (nbs <= 256);
    bool bf_ded = sort_ok && (ws_size >= needed_ded);
    bool bf_ovl = sort_ok && !bf_ded && (bf_bytes <= elistA_bytes);

    if (sort_ok) {
        int* counts_T   = (int*)d_ws;
        int* pubtick    = counts_T + n_scan;          // pub[256] + ticket[1]
        int* node_start = pubtick + 257;
        int2* elistA    = (int2*)((char*)d_ws + elist_off);
        uint_t* elistB4 = (uint_t*)((char*)d_ws + elist_off + elistA_bytes);
        uint_t* bfrow   = bf_ded ? (uint_t*)((char*)d_ws + needed_base)
                                 : (uint_t*)elistA;   // ovl: elistA dead after l2sort

        int ncvt = n_nodes * (D_FEAT / 2);
        // PRE: hist (+ fused cvt when dedicated bfrow) + zero pub/ticket
        int pre_grid = NL1 + (bf_ded ? CVT_BLOCKS : 0);
        mp_pre_kernel<<<pre_grid, 256, 0, stream>>>(
            edst, counts_T, n_edges, nb_buckets, pubtick,
            (const float2*)input, bfrow, bf_ded ? ncvt : 0);
        mp_scanlb_kernel<<<nbs, SCAN_T, 0, stream>>>(counts_T, n_scan,
                                                     pubtick, pubtick + 256);
        mp_l1scatter_kernel<<<NL1, 256, 0, stream>>>(esrc, edst, ew, counts_T,
                                                     elistA, n_edges, nb_buckets);
        mp_l2sort_kernel<<<nb_buckets, 256, 0, stream>>>(
            elistA, counts_T, elistB4, node_start, n_nodes, n_edges, nb_buckets);

        long long total = (long long)n_nodes * 64;
        if (bf_ded || bf_ovl) {
            if (bf_ovl)   // overlay: convert only after elistA is dead
                mp_cvt_kernel<<<(ncvt + 255) / 256, 256, 0, stream>>>(
                    (const float2*)input, bfrow, ncvt);
            mp_gather3_kernel<<<(int)((total + 255) / 256), 256, 0, stream>>>(
                input, bfrow, node_start, elistB4, out, n_nodes);
        } else {
            mp_gather2_kernel<<<(int)((total + 255) / 256), 256, 0, stream>>>(
                input, node_start, elistB4, out, n_nodes);
        }
    } else {
        int n4 = (n_nodes * D_FEAT) / 4;
        mp_copy_kernel<<<(n4 + 255) / 256, 256, 0, stream>>>(
            (const float4*)input, (float4*)out, n4);
        long long total = (long long)n_edges * 64;
        mp_scatter_kernel<<<(int)((total + 255) / 256), 256, 0, stream>>>(
            input, ew, esrc, edst, out, n_edges);
    }
}

// Round 11
// 110.378 us; speedup vs baseline: 1.3550x; 1.3550x over previous
//
#include <hip/hip_runtime.h>
#include <hip/hip_bf16.h>

#define D_FEAT 64
#define NPB 128              // nodes per bucket (dst >> 7)
#define NPB_SHIFT 7
#define NL1 256              // level-1 blocks
#define MAX_NB 1024          // max buckets supported by LDS arrays
#define SCAN_T 256
#define SCAN_PER_T 8
#define SCAN_CHUNK (SCAN_T * SCAN_PER_T)   // 2048
#define SRC_BITS 17
#define SRC_MASK 0x1FFFF
#define CVT_BLOCKS 2048
#define W_SCALE 32768.0f
#define W_INV (1.0f / 32768.0f)

typedef unsigned int uint_t;

__device__ inline unsigned short f32_to_bf16_rn(float f) {
    uint_t x = __float_as_uint(f);
    uint_t r = (x + 0x7fffu + ((x >> 16) & 1u)) >> 16;   // round-to-nearest-even
    return (unsigned short)r;
}

// ---------- PRE: fused dst-bucket histogram + (optional) bf16 convert ----------
// blocks [0, NL1): histogram of dst buckets into counts_T (transposed, +1 shift)
// blocks [NL1, NL1+CVT_BLOCKS): grid-stride convert input rows -> packed bf16x2
__global__ void mp_pre_kernel(const int* __restrict__ edst,
                              int* __restrict__ counts_T,
                              int n_edges, int nb_buckets,
                              const float2* __restrict__ in2,
                              uint_t* __restrict__ bfrow, int ncvt) {
    __shared__ int hist[MAX_NB];
    int t = threadIdx.x;
    if (blockIdx.x < NL1) {
        for (int k = t; k < nb_buckets; k += blockDim.x) hist[k] = 0;
        __syncthreads();
        int epb = (n_edges + NL1 - 1) / NL1;
        int lo = blockIdx.x * epb;
        int hi = min(n_edges, lo + epb);
        for (int i = lo + t; i < hi; i += blockDim.x)
            atomicAdd(&hist[edst[i] >> NPB_SHIFT], 1);
        __syncthreads();
        for (int k = t; k < nb_buckets; k += blockDim.x)
            counts_T[k * NL1 + blockIdx.x + 1] = hist[k];
        if (blockIdx.x == 0 && t == 0) counts_T[0] = 0;
    } else {
        int g0 = (blockIdx.x - NL1) * blockDim.x + t;
        int stride = CVT_BLOCKS * blockDim.x;
        for (int g = g0; g < ncvt; g += stride) {
            float2 v = in2[g];
            bfrow[g] = (uint_t)f32_to_bf16_rn(v.x) |
                       ((uint_t)f32_to_bf16_rn(v.y) << 16);
        }
    }
}

// ---------- multi-block inclusive scan (2 kernels) ----------
// scan1: per-block inclusive scan of a 2048 chunk; raw block sum -> partials[b]
__global__ void mp_scan1_kernel(int* __restrict__ a, int* __restrict__ partials, int n) {
    __shared__ int tsum[SCAN_T];
    int t = threadIdx.x;
    int base = blockIdx.x * SCAN_CHUNK + t * SCAN_PER_T;
    int v[SCAN_PER_T];
    int s = 0;
    #pragma unroll
    for (int j = 0; j < SCAN_PER_T; ++j) {
        int idx = base + j;
        v[j] = (idx < n) ? a[idx] : 0;
        s += v[j];
    }
    tsum[t] = s;
    __syncthreads();
    #pragma unroll
    for (int off = 1; off < SCAN_T; off <<= 1) {
        int u = (t >= off) ? tsum[t - off] : 0;
        __syncthreads();
        tsum[t] += u;
        __syncthreads();
    }
    if (t == SCAN_T - 1) partials[blockIdx.x] = tsum[t];
    int run = (t == 0) ? 0 : tsum[t - 1];
    #pragma unroll
    for (int j = 0; j < SCAN_PER_T; ++j) {
        int idx = base + j;
        run += v[j];
        if (idx < n) a[idx] = run;
    }
}

// scan3 (merged scan2): block b adds sum(partials[0..b-1]) to its chunk.
__global__ void mp_scan3_kernel(int* __restrict__ a, const int* __restrict__ partials, int n) {
    __shared__ int s[256];
    int b = blockIdx.x;
    if (b == 0) return;
    int t = threadIdx.x;
    s[t] = (t < b) ? partials[t] : 0;   // nbs <= 256 guaranteed
    __syncthreads();
    #pragma unroll
    for (int off = 128; off > 0; off >>= 1) {
        if (t < off) s[t] += s[t + off];
        __syncthreads();
    }
    int add = s[0];
    int base = b * SCAN_CHUNK + t * SCAN_PER_T;
    #pragma unroll
    for (int j = 0; j < SCAN_PER_T; ++j) {
        int idx = base + j;
        if (idx < n) a[idx] += add;
    }
}

// ---------- Level 1b: scatter edges into bucket order via LDS cursors ----------
__global__ void mp_l1scatter_kernel(const int* __restrict__ esrc,
                                    const int* __restrict__ edst,
                                    const float* __restrict__ ew,
                                    const int* __restrict__ counts_T,
                                    int2* __restrict__ elistA,
                                    int n_edges, int nb_buckets) {
    __shared__ int cur[MAX_NB];
    int t = threadIdx.x;
    for (int k = t; k < nb_buckets; k += blockDim.x)
        cur[k] = counts_T[k * NL1 + blockIdx.x];
    __syncthreads();
    int epb = (n_edges + NL1 - 1) / NL1;
    int lo = blockIdx.x * epb;
    int hi = min(n_edges, lo + epb);
    for (int i = lo + t; i < hi; i += blockDim.x) {
        int d = edst[i];
        int pos = atomicAdd(&cur[d >> NPB_SHIFT], 1);
        elistA[pos] = make_int2(esrc[i] | ((d & (NPB - 1)) << SRC_BITS),
                                __float_as_int(ew[i]));
    }
}

// ---------- Level 2: per-bucket counting sort -> per-node CSR, 4B records ----------
// elistB4[pos] = src(17b) | w_fixed15 << 17
__global__ void mp_l2sort_kernel(const int2* __restrict__ elistA,
                                 const int* __restrict__ counts_T,
                                 uint_t* __restrict__ elistB4,
                                 int* __restrict__ node_start,
                                 int n_nodes, int n_edges, int nb_buckets) {
    __shared__ int nh[NPB];
    __shared__ int cur[NPB];
    int k = blockIdx.x;
    int t = threadIdx.x;
    if (t < NPB) nh[t] = 0;
    __syncthreads();

    int base = counts_T[k * NL1];
    int end  = (k + 1 < nb_buckets) ? counts_T[(k + 1) * NL1] : n_edges;
    int cnt  = end - base;

    for (int i = t; i < cnt; i += 256)
        atomicAdd(&nh[elistA[base + i].x >> SRC_BITS], 1);
    __syncthreads();

    #pragma unroll
    for (int off = 1; off < NPB; off <<= 1) {
        int v = (t < NPB && t >= off) ? nh[t - off] : 0;
        __syncthreads();
        if (t < NPB) nh[t] += v;
        __syncthreads();
    }

    if (t < NPB) {
        int excl = base + ((t == 0) ? 0 : nh[t - 1]);
        cur[t] = excl;
        int g = k * NPB + t;
        if (g < n_nodes) node_start[g] = excl;
    }
    if (k == nb_buckets - 1 && t == 0) node_start[n_nodes] = n_edges;
    __syncthreads();

    for (int i = t; i < cnt; i += 256) {
        int2 r = elistA[base + i];
        int pos = atomicAdd(&cur[r.x >> SRC_BITS], 1);
        int w15 = (int)(__int_as_float(r.y) * W_SCALE + 0.5f);
        w15 = min(32767, max(0, w15));
        elistB4[pos] = (uint_t)(r.x & SRC_MASK) | ((uint_t)w15 << 17);
    }
}

// ---------- standalone cvt (used only when bfrow overlays elistA) ----------
__global__ void mp_cvt_kernel(const float2* __restrict__ in2,
                              uint_t* __restrict__ bfrow, int n) {
    int g = blockIdx.x * blockDim.x + threadIdx.x;
    if (g >= n) return;
    float2 v = in2[g];
    bfrow[g] = (uint_t)f32_to_bf16_rn(v.x) | ((uint_t)f32_to_bf16_rn(v.y) << 16);
}

// ---------- Gather (bf16 rows), 4B records, uniform shfl ----------
__global__ void mp_gather3_kernel(const float* __restrict__ input,
                                  const uint_t* __restrict__ bfrow,
                                  const int* __restrict__ node_start,
                                  const uint_t* __restrict__ elist4,
                                  float* __restrict__ out, int n_nodes) {
    int wid = (blockIdx.x * blockDim.x + threadIdx.x) >> 6;
    if (wid >= n_nodes) return;
    int lane = threadIdx.x & 63;
    int h = lane >> 5;
    int l5 = lane & 31;
    int b = node_start[wid];
    int cnt = node_start[wid + 1] - b;

    float ax = 0.0f, ay = 0.0f;
    for (int cbase = 0; cbase < cnt; cbase += 64) {
        int m = min(64, cnt - cbase);                  // >= 1, wave-uniform
        int rv = (int)elist4[b + cbase + min(lane, m - 1)];   // all lanes active
        int jp = 0;
        for (; jp + 16 <= m; jp += 16) {               // full 16-edge groups
            int   s[8];
            float w[8];
            uint_t u[8];
            #pragma unroll
            for (int q = 0; q < 8; ++q) {
                uint_t vq = (uint_t)__shfl(rv, jp + 2 * q + h, 64);
                s[q] = (int)(vq & SRC_MASK);
                w[q] = (float)(vq >> 17) * W_INV;
            }
            #pragma unroll
            for (int q = 0; q < 8; ++q)
                u[q] = bfrow[((uint_t)s[q] << 5) + l5];
            #pragma unroll
            for (int q = 0; q < 8; ++q) {
                ax = fmaf(__uint_as_float(u[q] << 16), w[q], ax);
                ay = fmaf(__uint_as_float(u[q] & 0xffff0000u), w[q], ay);
            }
        }
        // uniform tail: identical trip count in both halves; clamp shfl lane,
        // zero phantom weight.
        for (int j = jp; j < m; j += 2) {
            int jj = j + h;
            int jc = (jj < m) ? jj : (m - 1);
            uint_t vq = (uint_t)__shfl(rv, jc, 64);
            int sj = (int)(vq & SRC_MASK);
            float wj = (float)(vq >> 17) * W_INV;
            if (jj >= m) wj = 0.0f;
            uint_t uj = bfrow[((uint_t)sj << 5) + l5];
            ax = fmaf(__uint_as_float(uj << 16), wj, ax);
            ay = fmaf(__uint_as_float(uj & 0xffff0000u), wj, ay);
        }
    }
    ax += __shfl_xor(ax, 32, 64);
    ay += __shfl_xor(ay, 32, 64);
    if (h == 0) {
        float2 inp = ((const float2*)input)[((long long)wid << 5) + l5];
        float2 o;
        o.x = inp.x + ax;
        o.y = inp.y + ay;
        ((float2*)out)[((long long)wid << 5) + l5] = o;
    }
}

// ---------- Gather (f32 rows) fallback tier, 4B records ----------
__global__ void mp_gather2_kernel(const float* __restrict__ input,
                                  const int* __restrict__ node_start,
                                  const uint_t* __restrict__ elist4,
                                  float* __restrict__ out, int n_nodes) {
    int wid = (blockIdx.x * blockDim.x + threadIdx.x) >> 6;
    if (wid >= n_nodes) return;
    int lane = threadIdx.x & 63;
    int b = node_start[wid], e_end = node_start[wid + 1];
    float acc = input[(long long)wid * D_FEAT + lane];
    for (int i = b; i < e_end; ++i) {
        uint_t r = elist4[i];
        float w = (float)(r >> 17) * W_INV;
        acc += input[(long long)(r & SRC_MASK) * D_FEAT + lane] * w;
    }
    out[(long long)wid * D_FEAT + lane] = acc;
}

// ---------- last-resort fallback (atomic scatter) ----------
__global__ void mp_copy_kernel(const float4* __restrict__ in,
                               float4* __restrict__ out, int n4) {
    int i = blockIdx.x * blockDim.x + threadIdx.x;
    if (i < n4) out[i] = in[i];
}

__global__ void mp_scatter_kernel(const float* __restrict__ input,
                                  const float* __restrict__ ew,
                                  const int* __restrict__ esrc,
                                  const int* __restrict__ edst,
                                  float* __restrict__ out, int n_edges) {
    int tid = blockIdx.x * blockDim.x + threadIdx.x;
    int e = tid >> 6;
    if (e >= n_edges) return;
    int lane = tid & 63;
    float v = input[(long long)esrc[e] * D_FEAT + lane] * ew[e];
    atomicAdd(&out[(long long)edst[e] * D_FEAT + lane], v);
}

extern "C" void kernel_launch(void* const* d_in, const int* in_sizes, int n_in,
                              void* d_out, int out_size, void* d_ws, size_t ws_size,
                              hipStream_t stream) {
    const float* input = (const float*)d_in[0];
    const float* ew    = (const float*)d_in[1];
    const int* esrc    = (const int*)d_in[2];
    const int* edst    = (const int*)d_in[3];
    float* out = (float*)d_out;

    int n_nodes = in_sizes[0] / D_FEAT;   // 100000
    int n_edges = in_sizes[1];            // 1600000

    int nb_buckets = (n_nodes + NPB - 1) / NPB;          // 782
    int n_scan = nb_buckets * NL1 + 1;                   // 200193
    int nbs = (n_scan + SCAN_CHUNK - 1) / SCAN_CHUNK;    // 98

    // ws: counts_T[n_scan] | partials[256] | node_start[n+1] | pad
    //     | elistA (8B*E) | elistB4 (4B*E) | bfrow (12.8MB, dedicated or overlay A)
    size_t head_ints = (size_t)n_scan + 256 + (size_t)n_nodes + 1;
    size_t elist_off = (head_ints * 4 + 255) & ~(size_t)255;
    size_t elistA_bytes = (size_t)n_edges * 8;
    size_t elistB_bytes = (size_t)n_edges * 4;
    size_t needed_base = elist_off + elistA_bytes + elistB_bytes;
    size_t bf_bytes = (size_t)n_nodes * (D_FEAT * 2);    // 128B per row
    size_t needed_ded = needed_base + bf_bytes;

    bool sort_ok = (ws_size >= needed_base) && (nb_buckets <= MAX_NB) &&
                   (n_nodes <= (1 << SRC_BITS)) && (nbs <= 256);
    bool bf_ded = sort_ok && (ws_size >= needed_ded);
    bool bf_ovl = sort_ok && !bf_ded && (bf_bytes <= elistA_bytes);

    if (sort_ok) {
        int* counts_T   = (int*)d_ws;
        int* partials   = counts_T + n_scan;
        int* node_start = partials + 256;
        int2* elistA    = (int2*)((char*)d_ws + elist_off);
        uint_t* elistB4 = (uint_t*)((char*)d_ws + elist_off + elistA_bytes);
        uint_t* bfrow   = bf_ded ? (uint_t*)((char*)d_ws + needed_base)
                                 : (uint_t*)elistA;   // ovl: elistA dead after l2sort

        int ncvt = n_nodes * (D_FEAT / 2);
        // PRE: hist (+ fused cvt when dedicated bfrow)
        int pre_grid = NL1 + (bf_ded ? CVT_BLOCKS : 0);
        mp_pre_kernel<<<pre_grid, 256, 0, stream>>>(
            edst, counts_T, n_edges, nb_buckets,
            (const float2*)input, bfrow, bf_ded ? ncvt : 0);
        mp_scan1_kernel<<<nbs, SCAN_T, 0, stream>>>(counts_T, partials, n_scan);
        mp_scan3_kernel<<<nbs, SCAN_T, 0, stream>>>(counts_T, partials, n_scan);
        mp_l1scatter_kernel<<<NL1, 256, 0, stream>>>(esrc, edst, ew, counts_T,
                                                     elistA, n_edges, nb_buckets);
        mp_l2sort_kernel<<<nb_buckets, 256, 0, stream>>>(
            elistA, counts_T, elistB4, node_start, n_nodes, n_edges, nb_buckets);

        long long total = (long long)n_nodes * 64;
        if (bf_ded || bf_ovl) {
            if (bf_ovl)   // overlay: convert only after elistA is dead
                mp_cvt_kernel<<<(ncvt + 255) / 256, 256, 0, stream>>>(
                    (const float2*)input, bfrow, ncvt);
            mp_gather3_kernel<<<(int)((total + 255) / 256), 256, 0, stream>>>(
                input, bfrow, node_start, elistB4, out, n_nodes);
        } else {
            mp_gather2_kernel<<<(int)((total + 255) / 256), 256, 0, stream>>>(
                input, node_start, elistB4, out, n_nodes);
        }
    } else {
        int n4 = (n_nodes * D_FEAT) / 4;
        mp_copy_kernel<<<(n4 + 255) / 256, 256, 0, stream>>>(
            (const float4*)input, (float4*)out, n4);
        long long total = (long long)n_edges * 64;
        mp_scatter_kernel<<<(int)((total + 255) / 256), 256, 0, stream>>>(
            input, ew, esrc, edst, out, n_edges);
    }
}

// Round 12
// 104.495 us; speedup vs baseline: 1.4313x; 1.0563x over previous
//
#include <hip/hip_runtime.h>
#include <hip/hip_bf16.h>

#define D_FEAT 64
#define NPB 128              // nodes per bucket (dst >> 7)
#define NPB_SHIFT 7
#define NL1 256              // level-1 blocks
#define MAX_NB 1024          // max buckets supported by LDS arrays
#define SCAN_T 256
#define SCAN_PER_T 8
#define SCAN_CHUNK (SCAN_T * SCAN_PER_T)   // 2048
#define SRC_BITS 17
#define SRC_MASK 0x1FFFF
#define CVT_BLOCKS 2048
#define W_SCALE 32768.0f
#define W_INV (1.0f / 32768.0f)
#define SG_T 512             // sortgather block size (8 waves)
#define MAX_REC 8192         // LDS record capacity per bucket (32KB)

typedef unsigned int uint_t;

__device__ inline unsigned short f32_to_bf16_rn(float f) {
    uint_t x = __float_as_uint(f);
    uint_t r = (x + 0x7fffu + ((x >> 16) & 1u)) >> 16;   // round-to-nearest-even
    return (unsigned short)r;
}

// ---------- PRE: fused dst-bucket histogram + (optional) bf16 convert ----------
// blocks [0, NL1): histogram of dst buckets into counts_T (transposed, +1 shift)
// block 0 also zeros pub[256] for the single-launch scan.
// blocks [NL1, NL1+CVT_BLOCKS): grid-stride convert input rows -> packed bf16x2
__global__ void mp_pre_kernel(const int* __restrict__ edst,
                              int* __restrict__ counts_T,
                              int n_edges, int nb_buckets,
                              int* __restrict__ pub,
                              const float2* __restrict__ in2,
                              uint_t* __restrict__ bfrow, int ncvt) {
    __shared__ int hist[MAX_NB];
    int t = threadIdx.x;
    if (blockIdx.x < NL1) {
        if (blockIdx.x == 0)
            for (int i = t; i < 256; i += blockDim.x) pub[i] = 0;
        for (int k = t; k < nb_buckets; k += blockDim.x) hist[k] = 0;
        __syncthreads();
        int epb = (n_edges + NL1 - 1) / NL1;
        int lo = blockIdx.x * epb;
        int hi = min(n_edges, lo + epb);
        for (int i = lo + t; i < hi; i += blockDim.x)
            atomicAdd(&hist[edst[i] >> NPB_SHIFT], 1);
        __syncthreads();
        for (int k = t; k < nb_buckets; k += blockDim.x)
            counts_T[k * NL1 + blockIdx.x + 1] = hist[k];
        if (blockIdx.x == 0 && t == 0) counts_T[0] = 0;
    } else {
        int g0 = (blockIdx.x - NL1) * blockDim.x + t;
        int stride = CVT_BLOCKS * blockDim.x;
        for (int g = g0; g < ncvt; g += stride) {
            float2 v = in2[g];
            bfrow[g] = (uint_t)f32_to_bf16_rn(v.x) |
                       ((uint_t)f32_to_bf16_rn(v.y) << 16);
        }
    }
}

// ---------- single-launch inclusive scan (parallel publish + parallel wait) ----
// pub[b] = chunk b total + 1 (0 = not ready); all blocks co-resident (<=256).
__global__ void mp_scanP_kernel(int* __restrict__ a, int n,
                                int* __restrict__ pub) {
    __shared__ int tsum[SCAN_T];
    __shared__ int red[SCAN_T];
    int t = threadIdx.x, bid = blockIdx.x;
    int base = bid * SCAN_CHUNK + t * SCAN_PER_T;
    int v[SCAN_PER_T];
    int s = 0;
    #pragma unroll
    for (int j = 0; j < SCAN_PER_T; ++j) {
        int idx = base + j;
        v[j] = (idx < n) ? a[idx] : 0;
        s += v[j];
    }
    tsum[t] = s;
    __syncthreads();
    #pragma unroll
    for (int off = 1; off < SCAN_T; off <<= 1) {
        int u = (t >= off) ? tsum[t - off] : 0;
        __syncthreads();
        tsum[t] += u;
        __syncthreads();
    }
    if (t == SCAN_T - 1) atomicExch(&pub[bid], tsum[t] + 1);
    // parallel wait: thread t polls predecessor chunks t, t+256, ...
    int ls = 0;
    for (int i = t; i < bid; i += SCAN_T) {
        int p;
        while ((p = atomicAdd(&pub[i], 0)) == 0) {}
        ls += p - 1;
    }
    red[t] = ls;
    __syncthreads();
    #pragma unroll
    for (int off = 128; off > 0; off >>= 1) {
        if (t < off) red[t] += red[t + off];
        __syncthreads();
    }
    int run = red[0] + ((t == 0) ? 0 : tsum[t - 1]);
    #pragma unroll
    for (int j = 0; j < SCAN_PER_T; ++j) {
        int idx = base + j;
        run += v[j];
        if (idx < n) a[idx] = run;
    }
}

// ---------- Level 1b: scatter edges into bucket order via LDS cursors ----------
__global__ void mp_l1scatter_kernel(const int* __restrict__ esrc,
                                    const int* __restrict__ edst,
                                    const float* __restrict__ ew,
                                    const int* __restrict__ counts_T,
                                    int2* __restrict__ elistA,
                                    int n_edges, int nb_buckets) {
    __shared__ int cur[MAX_NB];
    int t = threadIdx.x;
    for (int k = t; k < nb_buckets; k += blockDim.x)
        cur[k] = counts_T[k * NL1 + blockIdx.x];
    __syncthreads();
    int epb = (n_edges + NL1 - 1) / NL1;
    int lo = blockIdx.x * epb;
    int hi = min(n_edges, lo + epb);
    for (int i = lo + t; i < hi; i += blockDim.x) {
        int d = edst[i];
        int pos = atomicAdd(&cur[d >> NPB_SHIFT], 1);
        elistA[pos] = make_int2(esrc[i] | ((d & (NPB - 1)) << SRC_BITS),
                                __float_as_int(ew[i]));
    }
}

// ---------- FUSED sort + gather: one block per bucket ----------
// Phase A: counting-sort the bucket's records into per-node order in LDS.
// Phase B: 8 waves gather 16 nodes each; records via LDS broadcast reads,
// bf16 rows (128B) fetched 8-deep per half-wave; out = input + acc.
__global__ void __launch_bounds__(SG_T)
mp_sortgather_kernel(const float* __restrict__ input,
                     const uint_t* __restrict__ bfrow,
                     const int2* __restrict__ elistA,
                     const int* __restrict__ counts_T,
                     float* __restrict__ out,
                     int n_nodes, int n_edges, int nb_buckets) {
    __shared__ int nh[NPB];
    __shared__ int cur[NPB];
    __shared__ uint_t rec[MAX_REC];
    int k = blockIdx.x;
    int t = threadIdx.x;
    int base = counts_T[k * NL1];
    int end  = (k + 1 < nb_buckets) ? counts_T[(k + 1) * NL1] : n_edges;
    int cnt  = end - base;

    int wv = t >> 6;
    int lane = t & 63;
    int h = lane >> 5, l5 = lane & 31;

    if (cnt <= MAX_REC) {
        if (t < NPB) nh[t] = 0;
        __syncthreads();
        for (int i = t; i < cnt; i += SG_T)
            atomicAdd(&nh[(elistA[base + i].x >> SRC_BITS) & (NPB - 1)], 1);
        __syncthreads();
        #pragma unroll
        for (int off = 1; off < NPB; off <<= 1) {
            int v = (t < NPB && t >= off) ? nh[t - off] : 0;
            __syncthreads();
            if (t < NPB) nh[t] += v;
            __syncthreads();
        }
        if (t < NPB) cur[t] = (t == 0) ? 0 : nh[t - 1];
        __syncthreads();
        for (int i = t; i < cnt; i += SG_T) {
            int2 r = elistA[base + i];
            int node = (r.x >> SRC_BITS) & (NPB - 1);
            int pos = atomicAdd(&cur[node], 1);
            int w15 = (int)(__int_as_float(r.y) * W_SCALE + 0.5f);
            w15 = min(32767, max(0, w15));
            rec[pos] = (uint_t)(r.x & SRC_MASK) | ((uint_t)w15 << 17);
        }
        __syncthreads();

        for (int node = wv; node < NPB; node += (SG_T / 64)) {
            int g = k * NPB + node;
            if (g >= n_nodes) break;              // wave-uniform
            int sb = (node == 0) ? 0 : nh[node - 1];
            int cn = nh[node] - sb;
            float ax = 0.0f, ay = 0.0f;
            int j = 0;
            for (; j + 16 <= cn; j += 16) {
                uint_t rr[8], u[8];
                #pragma unroll
                for (int q = 0; q < 8; ++q) rr[q] = rec[sb + j + 2 * q + h];
                #pragma unroll
                for (int q = 0; q < 8; ++q)
                    u[q] = bfrow[((rr[q] & SRC_MASK) << 5) + l5];
                #pragma unroll
                for (int q = 0; q < 8; ++q) {
                    float w = (float)(rr[q] >> 17) * W_INV;
                    ax = fmaf(__uint_as_float(u[q] << 16), w, ax);
                    ay = fmaf(__uint_as_float(u[q] & 0xffff0000u), w, ay);
                }
            }
            for (; j < cn; j += 2) {
                int jj = j + h;
                if (jj < cn) {                    // halves may diverge: no shfl here
                    uint_t rr = rec[sb + jj];
                    uint_t u = bfrow[((rr & SRC_MASK) << 5) + l5];
                    float w = (float)(rr >> 17) * W_INV;
                    ax = fmaf(__uint_as_float(u << 16), w, ax);
                    ay = fmaf(__uint_as_float(u & 0xffff0000u), w, ay);
                }
            }
            ax += __shfl_xor(ax, 32, 64);
            ay += __shfl_xor(ay, 32, 64);
            if (h == 0) {
                float2 inp = ((const float2*)input)[((long long)g << 5) + l5];
                float2 o;
                o.x = inp.x + ax;
                o.y = inp.y + ay;
                ((float2*)out)[((long long)g << 5) + l5] = o;
            }
        }
    } else {
        // pathological bucket (cnt > MAX_REC): correct slow path, O(cnt) per node.
        for (int node = wv; node < NPB; node += (SG_T / 64)) {
            int g = k * NPB + node;
            if (g >= n_nodes) break;
            float ax = 0.0f, ay = 0.0f;
            for (int i = h; i < cnt; i += 2) {
                int2 r = elistA[base + i];
                if (((r.x >> SRC_BITS) & (NPB - 1)) == node) {
                    uint_t u = bfrow[(((uint_t)r.x & SRC_MASK) << 5) + l5];
                    float w = __int_as_float(r.y);
                    ax = fmaf(__uint_as_float(u << 16), w, ax);
                    ay = fmaf(__uint_as_float(u & 0xffff0000u), w, ay);
                }
            }
            ax += __shfl_xor(ax, 32, 64);
            ay += __shfl_xor(ay, 32, 64);
            if (h == 0) {
                float2 inp = ((const float2*)input)[((long long)g << 5) + l5];
                float2 o;
                o.x = inp.x + ax;
                o.y = inp.y + ay;
                ((float2*)out)[((long long)g << 5) + l5] = o;
            }
        }
    }
}

// ---------- fallback tier: separate l2sort + gather3 (round-11 path) ----------
__global__ void mp_l2sort_kernel(const int2* __restrict__ elistA,
                                 const int* __restrict__ counts_T,
                                 uint_t* __restrict__ elistB4,
                                 int* __restrict__ node_start,
                                 int n_nodes, int n_edges, int nb_buckets) {
    __shared__ int nh[NPB];
    __shared__ int cur[NPB];
    int k = blockIdx.x;
    int t = threadIdx.x;
    if (t < NPB) nh[t] = 0;
    __syncthreads();
    int base = counts_T[k * NL1];
    int end  = (k + 1 < nb_buckets) ? counts_T[(k + 1) * NL1] : n_edges;
    int cnt  = end - base;
    for (int i = t; i < cnt; i += 256)
        atomicAdd(&nh[elistA[base + i].x >> SRC_BITS], 1);
    __syncthreads();
    #pragma unroll
    for (int off = 1; off < NPB; off <<= 1) {
        int v = (t < NPB && t >= off) ? nh[t - off] : 0;
        __syncthreads();
        if (t < NPB) nh[t] += v;
        __syncthreads();
    }
    if (t < NPB) {
        int excl = base + ((t == 0) ? 0 : nh[t - 1]);
        cur[t] = excl;
        int g = k * NPB + t;
        if (g < n_nodes) node_start[g] = excl;
    }
    if (k == nb_buckets - 1 && t == 0) node_start[n_nodes] = n_edges;
    __syncthreads();
    for (int i = t; i < cnt; i += 256) {
        int2 r = elistA[base + i];
        int pos = atomicAdd(&cur[r.x >> SRC_BITS], 1);
        int w15 = (int)(__int_as_float(r.y) * W_SCALE + 0.5f);
        w15 = min(32767, max(0, w15));
        elistB4[pos] = (uint_t)(r.x & SRC_MASK) | ((uint_t)w15 << 17);
    }
}

__global__ void mp_cvt_kernel(const float2* __restrict__ in2,
                              uint_t* __restrict__ bfrow, int n) {
    int g = blockIdx.x * blockDim.x + threadIdx.x;
    if (g >= n) return;
    float2 v = in2[g];
    bfrow[g] = (uint_t)f32_to_bf16_rn(v.x) | ((uint_t)f32_to_bf16_rn(v.y) << 16);
}

__global__ void mp_gather3_kernel(const float* __restrict__ input,
                                  const uint_t* __restrict__ bfrow,
                                  const int* __restrict__ node_start,
                                  const uint_t* __restrict__ elist4,
                                  float* __restrict__ out, int n_nodes) {
    int wid = (blockIdx.x * blockDim.x + threadIdx.x) >> 6;
    if (wid >= n_nodes) return;
    int lane = threadIdx.x & 63;
    int h = lane >> 5;
    int l5 = lane & 31;
    int b = node_start[wid];
    int cnt = node_start[wid + 1] - b;
    float ax = 0.0f, ay = 0.0f;
    for (int cbase = 0; cbase < cnt; cbase += 64) {
        int m = min(64, cnt - cbase);
        int rv = (int)elist4[b + cbase + min(lane, m - 1)];
        int jp = 0;
        for (; jp + 16 <= m; jp += 16) {
            int s[8]; float w[8]; uint_t u[8];
            #pragma unroll
            for (int q = 0; q < 8; ++q) {
                uint_t vq = (uint_t)__shfl(rv, jp + 2 * q + h, 64);
                s[q] = (int)(vq & SRC_MASK);
                w[q] = (float)(vq >> 17) * W_INV;
            }
            #pragma unroll
            for (int q = 0; q < 8; ++q)
                u[q] = bfrow[((uint_t)s[q] << 5) + l5];
            #pragma unroll
            for (int q = 0; q < 8; ++q) {
                ax = fmaf(__uint_as_float(u[q] << 16), w[q], ax);
                ay = fmaf(__uint_as_float(u[q] & 0xffff0000u), w[q], ay);
            }
        }
        for (int j = jp; j < m; j += 2) {
            int jj = j + h;
            int jc = (jj < m) ? jj : (m - 1);
            uint_t vq = (uint_t)__shfl(rv, jc, 64);
            int sj = (int)(vq & SRC_MASK);
            float wj = (float)(vq >> 17) * W_INV;
            if (jj >= m) wj = 0.0f;
            uint_t uj = bfrow[((uint_t)sj << 5) + l5];
            ax = fmaf(__uint_as_float(uj << 16), wj, ax);
            ay = fmaf(__uint_as_float(uj & 0xffff0000u), wj, ay);
        }
    }
    ax += __shfl_xor(ax, 32, 64);
    ay += __shfl_xor(ay, 32, 64);
    if (h == 0) {
        float2 inp = ((const float2*)input)[((long long)wid << 5) + l5];
        float2 o;
        o.x = inp.x + ax;
        o.y = inp.y + ay;
        ((float2*)out)[((long long)wid << 5) + l5] = o;
    }
}

__global__ void mp_gather2_kernel(const float* __restrict__ input,
                                  const int* __restrict__ node_start,
                                  const uint_t* __restrict__ elist4,
                                  float* __restrict__ out, int n_nodes) {
    int wid = (blockIdx.x * blockDim.x + threadIdx.x) >> 6;
    if (wid >= n_nodes) return;
    int lane = threadIdx.x & 63;
    int b = node_start[wid], e_end = node_start[wid + 1];
    float acc = input[(long long)wid * D_FEAT + lane];
    for (int i = b; i < e_end; ++i) {
        uint_t r = elist4[i];
        float w = (float)(r >> 17) * W_INV;
        acc += input[(long long)(r & SRC_MASK) * D_FEAT + lane] * w;
    }
    out[(long long)wid * D_FEAT + lane] = acc;
}

// ---------- last-resort fallback (atomic scatter) ----------
__global__ void mp_copy_kernel(const float4* __restrict__ in,
                               float4* __restrict__ out, int n4) {
    int i = blockIdx.x * blockDim.x + threadIdx.x;
    if (i < n4) out[i] = in[i];
}

__global__ void mp_scatter_kernel(const float* __restrict__ input,
                                  const float* __restrict__ ew,
                                  const int* __restrict__ esrc,
                                  const int* __restrict__ edst,
                                  float* __restrict__ out, int n_edges) {
    int tid = blockIdx.x * blockDim.x + threadIdx.x;
    int e = tid >> 6;
    if (e >= n_edges) return;
    int lane = tid & 63;
    float v = input[(long long)esrc[e] * D_FEAT + lane] * ew[e];
    atomicAdd(&out[(long long)edst[e] * D_FEAT + lane], v);
}

extern "C" void kernel_launch(void* const* d_in, const int* in_sizes, int n_in,
                              void* d_out, int out_size, void* d_ws, size_t ws_size,
                              hipStream_t stream) {
    const float* input = (const float*)d_in[0];
    const float* ew    = (const float*)d_in[1];
    const int* esrc    = (const int*)d_in[2];
    const int* edst    = (const int*)d_in[3];
    float* out = (float*)d_out;

    int n_nodes = in_sizes[0] / D_FEAT;   // 100000
    int n_edges = in_sizes[1];            // 1600000

    int nb_buckets = (n_nodes + NPB - 1) / NPB;          // 782
    int n_scan = nb_buckets * NL1 + 1;                   // 200193
    int nbs = (n_scan + SCAN_CHUNK - 1) / SCAN_CHUNK;    // 98

    // ws: counts_T[n_scan] | pub[256] | node_start[n+1] | pad
    //     | elistA (8B*E) | { bfrow (fused) | elistB4+bfrow (fallback) }
    size_t head_ints = (size_t)n_scan + 256 + (size_t)n_nodes + 1;
    size_t elist_off = (head_ints * 4 + 255) & ~(size_t)255;
    size_t elistA_bytes = (size_t)n_edges * 8;
    size_t elistB_bytes = (size_t)n_edges * 4;
    size_t bf_bytes = (size_t)n_nodes * (D_FEAT * 2);    // 128B per row

    size_t needed_fused = elist_off + elistA_bytes + bf_bytes;
    size_t needed_base  = elist_off + elistA_bytes + elistB_bytes;
    size_t needed_ded   = needed_base + bf_bytes;

    bool params_ok = (nb_buckets <= MAX_NB) && (n_nodes <= (1 << SRC_BITS)) &&
                     (nbs <= 256);
    bool fused_ok = params_ok && (ws_size >= needed_fused);
    bool sort_ok  = params_ok && (ws_size >= needed_base);
    bool bf_ded   = sort_ok && (ws_size >= needed_ded);
    bool bf_ovl   = sort_ok && !bf_ded && (bf_bytes <= elistA_bytes);

    if (fused_ok) {
        int* counts_T = (int*)d_ws;
        int* pub      = counts_T + n_scan;
        int2* elistA  = (int2*)((char*)d_ws + elist_off);
        uint_t* bfrow = (uint_t*)((char*)d_ws + elist_off + elistA_bytes);
        int ncvt = n_nodes * (D_FEAT / 2);

        mp_pre_kernel<<<NL1 + CVT_BLOCKS, 256, 0, stream>>>(
            edst, counts_T, n_edges, nb_buckets, pub,
            (const float2*)input, bfrow, ncvt);
        mp_scanP_kernel<<<nbs, SCAN_T, 0, stream>>>(counts_T, n_scan, pub);
        mp_l1scatter_kernel<<<NL1, 256, 0, stream>>>(esrc, edst, ew, counts_T,
                                                     elistA, n_edges, nb_buckets);
        mp_sortgather_kernel<<<nb_buckets, SG_T, 0, stream>>>(
            input, bfrow, elistA, counts_T, out, n_nodes, n_edges, nb_buckets);
    } else if (sort_ok) {
        int* counts_T   = (int*)d_ws;
        int* pub        = counts_T + n_scan;
        int* node_start = pub + 256;
        int2* elistA    = (int2*)((char*)d_ws + elist_off);
        uint_t* elistB4 = (uint_t*)((char*)d_ws + elist_off + elistA_bytes);
        uint_t* bfrow   = bf_ded ? (uint_t*)((char*)d_ws + needed_base)
                                 : (uint_t*)elistA;   // ovl: elistA dead after l2sort
        int ncvt = n_nodes * (D_FEAT / 2);

        int pre_grid = NL1 + (bf_ded ? CVT_BLOCKS : 0);
        mp_pre_kernel<<<pre_grid, 256, 0, stream>>>(
            edst, counts_T, n_edges, nb_buckets, pub,
            (const float2*)input, bfrow, bf_ded ? ncvt : 0);
        mp_scanP_kernel<<<nbs, SCAN_T, 0, stream>>>(counts_T, n_scan, pub);
        mp_l1scatter_kernel<<<NL1, 256, 0, stream>>>(esrc, edst, ew, counts_T,
                                                     elistA, n_edges, nb_buckets);
        mp_l2sort_kernel<<<nb_buckets, 256, 0, stream>>>(
            elistA, counts_T, elistB4, node_start, n_nodes, n_edges, nb_buckets);

        long long total = (long long)n_nodes * 64;
        if (bf_ded || bf_ovl) {
            if (bf_ovl)
                mp_cvt_kernel<<<(ncvt + 255) / 256, 256, 0, stream>>>(
                    (const float2*)input, bfrow, ncvt);
            mp_gather3_kernel<<<(int)((total + 255) / 256), 256, 0, stream>>>(
                input, bfrow, node_start, elistB4, out, n_nodes);
        } else {
            mp_gather2_kernel<<<(int)((total + 255) / 256), 256, 0, stream>>>(
                input, node_start, elistB4, out, n_nodes);
        }
    } else {
        int n4 = (n_nodes * D_FEAT) / 4;
        mp_copy_kernel<<<(n4 + 255) / 256, 256, 0, stream>>>(
            (const float4*)input, (float4*)out, n4);
        long long total = (long long)n_edges * 64;
        mp_scatter_kernel<<<(int)((total + 255) / 256), 256, 0, stream>>>(
            input, ew, esrc, edst, out, n_edges);
    }
}